// Round 6
// baseline (930.017 us; speedup 1.0000x reference)
//
#include <hip/hip_runtime.h>
#include <math.h>

#define N_NODES 100000
#define IN_DIM  128
#define HIDDEN  64
#define N_EDGES 1600000

// ---------------------------------------------------------------------------
// Workspace layout (4-byte units):
//   [0,       100000)   weights  (float)  per-node gate
//   [100000,  200000)   counts   (int)    per-node in-degree
//   [200000,  300000)   cursor   (int)    per-node fill cursor
//   [300000,  300016)   counter  (int)    global bump allocator
//   [300016,  400016)   base     (int)    per-node segment base in bucket
//   [400016, 2000016)   bucket   (int)    edge source (col) grouped by row
// ---------------------------------------------------------------------------
#define WS_WEIGHTS 0
#define WS_COUNTS  100000
#define WS_CURSOR  200000
#define WS_COUNTER 300000
#define WS_BASE    300016
#define WS_BUCKET  400016
#define WS_TOTAL   2000016

__global__ __launch_bounds__(256) void zero_int_kernel(int* __restrict__ p, int n)
{
    const int i = blockIdx.x * 256 + threadIdx.x;
    if (i < n) p[i] = 0;
}

__global__ __launch_bounds__(256) void zero_f4_kernel(float4* __restrict__ p, int n4)
{
    const int i = blockIdx.x * 256 + threadIdx.x;
    if (i < n4) p[i] = make_float4(0.f, 0.f, 0.f, 0.f);
}

// ---------------------------------------------------------------------------
// Gate v4: wave-level hidden-half split for 2x wave count.
// Block = 256 thr = 4 waves; waves {0,1} -> nodes [0,64), waves {2,3} ->
// nodes [64,128). wave&1 picks hidden-half [0,32) vs [32,64) -> W_sim
// addresses stay wave-uniform (SGPR operand FMAs preserved).
// Partial gate sums combined through LDS. Node clamped (no early return
// before barrier); duplicate writes in last block store identical values.
// ---------------------------------------------------------------------------
__global__ __launch_bounds__(256) void gate_kernel(
    const float* __restrict__ x, const float* __restrict__ W_sim,
    const float* __restrict__ b_sim, const float* __restrict__ w_vec,
    const float* __restrict__ b_vec, float* __restrict__ weights)
{
    __shared__ float gp[4][64];
    const int wave = threadIdx.x >> 6;
    const int lane = threadIdx.x & 63;
    const int grp  = wave >> 1;
    const int jh   = wave & 1;       // hidden-half (wave-uniform)
    int node = blockIdx.x * 128 + grp * 64 + lane;
    if (node >= N_NODES) node = N_NODES - 1;

    const float4* xr = (const float4*)(x + (size_t)node * IN_DIM);

    float g = 0.f;
#pragma unroll
    for (int jc = 0; jc < 32; jc += 16) {
        const int j0 = jh * 32 + jc;
        float acc[16];
#pragma unroll
        for (int jj = 0; jj < 16; ++jj) acc[jj] = b_sim[j0 + jj];
        for (int k4 = 0; k4 < IN_DIM / 4; ++k4) {
            const float4 a = xr[k4];
#pragma unroll
            for (int jj = 0; jj < 16; ++jj) {
                acc[jj] += a.x * W_sim[(4 * k4 + 0) * HIDDEN + j0 + jj];
                acc[jj] += a.y * W_sim[(4 * k4 + 1) * HIDDEN + j0 + jj];
                acc[jj] += a.z * W_sim[(4 * k4 + 2) * HIDDEN + j0 + jj];
                acc[jj] += a.w * W_sim[(4 * k4 + 3) * HIDDEN + j0 + jj];
            }
        }
#pragma unroll
        for (int jj = 0; jj < 16; ++jj)
            g += tanhf(acc[jj]) * w_vec[j0 + jj];
    }
    gp[wave][lane] = g;
    __syncthreads();
    if (jh == 0) {
        const float gt = gp[wave][lane] + gp[wave + 1][lane] + b_vec[0];
        weights[node] = 1.f / (1.f + expf(-gt));
    }
}

// ---------------------------------------------------------------------------
// Binning: histogram -> segment alloc -> bucket fill.
// ---------------------------------------------------------------------------
__global__ __launch_bounds__(256) void hist_kernel(
    const int* __restrict__ edge_index, int* __restrict__ counts)
{
    const int e = blockIdx.x * 256 + threadIdx.x;
    if (e < N_EDGES) atomicAdd(&counts[edge_index[e]], 1);
}

__global__ __launch_bounds__(256) void alloc_kernel(
    const int* __restrict__ counts, int* __restrict__ base, int* __restrict__ counter)
{
    const int node = blockIdx.x * 256 + threadIdx.x;
    const int lane = threadIdx.x & 63;
    const int c = (node < N_NODES) ? counts[node] : 0;

    int incl = c;
#pragma unroll
    for (int off = 1; off < 64; off <<= 1) {
        int v = __shfl_up(incl, off, 64);
        if (lane >= off) incl += v;
    }
    const int excl = incl - c;
    int wbase = 0;
    if (lane == 63) wbase = atomicAdd(counter, incl);
    wbase = __shfl(wbase, 63, 64);

    if (node < N_NODES) base[node] = wbase + excl;
}

__global__ __launch_bounds__(256) void fill_kernel(
    const int* __restrict__ edge_index, const int* __restrict__ base,
    int* __restrict__ cursor, int* __restrict__ bucket)
{
    const int e = blockIdx.x * 256 + threadIdx.x;
    if (e >= N_EDGES) return;
    const int row = edge_index[e];
    const int col = edge_index[N_EDGES + e];
    const int pos = atomicAdd(&cursor[row], 1);
    bucket[base[row] + pos] = col;
}

// ---------------------------------------------------------------------------
// Gather v2: one wave per node, half-wave edge pairing (unchanged from R5).
// ---------------------------------------------------------------------------
__global__ __launch_bounds__(256) void gather_kernel(
    const float* __restrict__ x, const float* __restrict__ weights,
    const int* __restrict__ counts, const int* __restrict__ base,
    const int* __restrict__ bucket, float* __restrict__ readout)
{
    const int wave = threadIdx.x >> 6;
    const int lane = threadIdx.x & 63;
    const int half = lane >> 5;
    const int l32  = lane & 31;
    const int node = blockIdx.x * 4 + wave;
    if (node >= N_NODES) return;

    const int m = counts[node];
    const int b = base[node];

    float4 acc = make_float4(0.f, 0.f, 0.f, 0.f);
    for (int i = half; i < m; i += 2) {
        const int col = bucket[b + i];
        const float w = weights[col];
        const float4 xv = ((const float4*)(x + (size_t)col * IN_DIM))[l32];
        acc.x += xv.x * w;
        acc.y += xv.y * w;
        acc.z += xv.z * w;
        acc.w += xv.w * w;
    }
    acc.x += __shfl(acc.x, lane ^ 32, 64);
    acc.y += __shfl(acc.y, lane ^ 32, 64);
    acc.z += __shfl(acc.z, lane ^ 32, 64);
    acc.w += __shfl(acc.w, lane ^ 32, 64);

    if (half == 0)
        ((float4*)(readout + (size_t)node * IN_DIM))[l32] = acc;
}

// ---------------------------------------------------------------------------
// Fallback scatter (only if ws too small for binning).
// ---------------------------------------------------------------------------
__global__ __launch_bounds__(256) void scatter_kernel(
    const float* __restrict__ x, const int* __restrict__ edge_index,
    const float* __restrict__ weights, float* __restrict__ readout)
{
    const int gid = blockIdx.x * 256 + threadIdx.x;
    const int e = gid >> 5;
    const int c = gid & 31;
    if (e >= N_EDGES) return;
    const int row = edge_index[e];
    const int col = edge_index[N_EDGES + e];
    const float w = weights[col];
    const float4 xv = ((const float4*)(x + (size_t)col * IN_DIM))[c];
    float* dst = readout + (size_t)row * IN_DIM + c * 4;
    atomicAdd(dst + 0, xv.x * w);
    atomicAdd(dst + 1, xv.y * w);
    atomicAdd(dst + 2, xv.z * w);
    atomicAdd(dst + 3, xv.w * w);
}

// ---------------------------------------------------------------------------
// Prompt v5: wave-level output-half split for 2x wave count.
// Block = 256 thr = 4 waves; waves {0,1} -> nodes [0,64), {2,3} -> [64,128).
// Both waves of a pair compute the full h (layer1 duplicated — we are
// latency-bound, not FLOP-bound); wave&1 picks the layer2 output half, so
// W2 addresses stay wave-uniform (SGPR-operand FMAs).
// __syncthreads() between layers: all rr (=out) reads drain before any
// out writes -> in-place safe across the wave pair. Node clamped; no early
// return before the barrier.
// ---------------------------------------------------------------------------
__global__ __launch_bounds__(256) void prompt_kernel(
    const float* __restrict__ x, float* __restrict__ out /* = readout */,
    const float* __restrict__ W1, const float* __restrict__ b1,
    const float* __restrict__ W2, const float* __restrict__ b2)
{
    const int wave = threadIdx.x >> 6;
    const int lane = threadIdx.x & 63;
    const int grp  = wave >> 1;
    const int oh   = wave & 1;       // output half (wave-uniform)
    int node = blockIdx.x * 128 + grp * 64 + lane;
    if (node >= N_NODES) node = N_NODES - 1;

    const float4* rr = (const float4*)(out + (size_t)node * IN_DIM);

    float h[HIDDEN];
#pragma unroll
    for (int jc = 0; jc < HIDDEN; jc += 16) {
        float acc[16];
#pragma unroll
        for (int jj = 0; jj < 16; ++jj) acc[jj] = b1[jc + jj];
        for (int k4 = 0; k4 < IN_DIM / 4; ++k4) {
            const float4 a = rr[k4];
#pragma unroll
            for (int jj = 0; jj < 16; ++jj) {
                acc[jj] += a.x * W1[(4 * k4 + 0) * HIDDEN + jc + jj];
                acc[jj] += a.y * W1[(4 * k4 + 1) * HIDDEN + jc + jj];
                acc[jj] += a.z * W1[(4 * k4 + 2) * HIDDEN + jc + jj];
                acc[jj] += a.w * W1[(4 * k4 + 3) * HIDDEN + jc + jj];
            }
        }
#pragma unroll
        for (int jj = 0; jj < 16; ++jj)
            h[jc + jj] = fmaxf(acc[jj], 0.f);
    }

    __syncthreads();   // drain all readout reads before in-place writes

    const int c0 = oh * 64;          // this wave's output column base
    const float4* xr4 = (const float4*)(x + (size_t)node * IN_DIM);
    float4* or4 = (float4*)(out + (size_t)node * IN_DIM);

    for (int jc = 0; jc < 64; jc += 16) {
        float acc[16];
#pragma unroll
        for (int jj = 0; jj < 16; ++jj) acc[jj] = b2[c0 + jc + jj];
#pragma unroll
        for (int k2 = 0; k2 < HIDDEN; ++k2) {
            const float hk = h[k2];
#pragma unroll
            for (int jj = 0; jj < 16; ++jj)
                acc[jj] += hk * W2[k2 * IN_DIM + c0 + jc + jj];
        }
#pragma unroll
        for (int q = 0; q < 4; ++q) {
            const float4 xv = xr4[(c0 + jc) / 4 + q];
            float4 o;
            o.x = xv.x + acc[4 * q + 0];
            o.y = xv.y + acc[4 * q + 1];
            o.z = xv.z + acc[4 * q + 2];
            o.w = xv.w + acc[4 * q + 3];
            or4[(c0 + jc) / 4 + q] = o;
        }
    }
}

// ---------------------------------------------------------------------------
extern "C" void kernel_launch(void* const* d_in, const int* in_sizes, int n_in,
                              void* d_out, int out_size, void* d_ws, size_t ws_size,
                              hipStream_t stream)
{
    const float* x          = (const float*)d_in[0];
    const int*   edge_index = (const int*)d_in[1];   // int32 (JAX x64 disabled)
    const float* W_sim      = (const float*)d_in[2];
    const float* b_sim      = (const float*)d_in[3];
    const float* w_vec      = (const float*)d_in[4];
    const float* b_vec      = (const float*)d_in[5];
    const float* W1         = (const float*)d_in[6];
    const float* b1         = (const float*)d_in[7];
    const float* W2         = (const float*)d_in[8];
    const float* b2         = (const float*)d_in[9];

    float* out = (float*)d_out;
    float* wsf = (float*)d_ws;
    int*   wsi = (int*)d_ws;

    float* weights = wsf + WS_WEIGHTS;

    const int nodeBlocks = (N_NODES + 127) / 128;   // 128 nodes per block
    gate_kernel<<<nodeBlocks, 256, 0, stream>>>(x, W_sim, b_sim, w_vec, b_vec, weights);

    if (ws_size >= (size_t)WS_TOTAL * 4) {
        int* counts  = wsi + WS_COUNTS;
        int* cursor  = wsi + WS_CURSOR;
        int* counter = wsi + WS_COUNTER;
        int* base    = wsi + WS_BASE;
        int* bucket  = wsi + WS_BUCKET;

        const int nz = WS_BASE - WS_COUNTS;  // counts+cursor+counter contiguous
        zero_int_kernel<<<(nz + 255) / 256, 256, 0, stream>>>(wsi + WS_COUNTS, nz);

        hist_kernel<<<(N_EDGES + 255) / 256, 256, 0, stream>>>(edge_index, counts);
        alloc_kernel<<<(N_NODES + 255) / 256, 256, 0, stream>>>(counts, base, counter);
        fill_kernel<<<(N_EDGES + 255) / 256, 256, 0, stream>>>(edge_index, base, cursor, bucket);
        gather_kernel<<<N_NODES / 4, 256, 0, stream>>>(x, weights, counts, base, bucket, out);
    } else {
        const int n4 = N_NODES * IN_DIM / 4;
        zero_f4_kernel<<<(n4 + 255) / 256, 256, 0, stream>>>((float4*)out, n4);
        scatter_kernel<<<(N_EDGES * 32) / 256, 256, 0, stream>>>(x, edge_index, weights, out);
    }

    prompt_kernel<<<nodeBlocks, 256, 0, stream>>>(x, out, W1, b1, W2, b2);
}

// Round 7
// 559.364 us; speedup vs baseline: 1.6626x; 1.6626x over previous
//
#include <hip/hip_runtime.h>
#include <math.h>

#define N_NODES 100000
#define IN_DIM  128
#define HIDDEN  64
#define N_EDGES 1600000

// ---------------------------------------------------------------------------
// Workspace layout (4-byte units):
//   [0,       100000)   weights  (float)  per-node gate
//   [100000,  200000)   counts   (int)    per-node in-degree
//   [200000,  300000)   cursor   (int)    per-node fill cursor
//   [300000,  300016)   counter  (int)    global bump allocator
//   [300016,  400016)   base     (int)    per-node segment base in bucket
//   [400016, 2000016)   bucket   (int)    edge source (col) grouped by row
// ---------------------------------------------------------------------------
#define WS_WEIGHTS 0
#define WS_COUNTS  100000
#define WS_CURSOR  200000
#define WS_COUNTER 300000
#define WS_BASE    300016
#define WS_BUCKET  400016
#define WS_TOTAL   2000016

__global__ __launch_bounds__(256) void zero_int_kernel(int* __restrict__ p, int n)
{
    const int i = blockIdx.x * 256 + threadIdx.x;
    if (i < n) p[i] = 0;
}

__global__ __launch_bounds__(256) void zero_f4_kernel(float4* __restrict__ p, int n4)
{
    const int i = blockIdx.x * 256 + threadIdx.x;
    if (i < n4) p[i] = make_float4(0.f, 0.f, 0.f, 0.f);
}

// ---------------------------------------------------------------------------
// Gate v5: one THREAD per node, SINGLE k-sweep with acc[64] fully resident.
// Row is loaded once (32 float4) instead of 4x. W_sim addresses are
// lane-invariant -> scalar loads; FMAs carry weights as the SGPR operand.
// Every loop that indexes acc[] is fully unrolled (R4 lesson: dynamic
// indexing demotes to scratch).
// ---------------------------------------------------------------------------
__global__ __launch_bounds__(256) void gate_kernel(
    const float* __restrict__ x, const float* __restrict__ W_sim,
    const float* __restrict__ b_sim, const float* __restrict__ w_vec,
    const float* __restrict__ b_vec, float* __restrict__ weights)
{
    const int node = blockIdx.x * 256 + threadIdx.x;
    if (node >= N_NODES) return;
    const float4* xr = (const float4*)(x + (size_t)node * IN_DIM);

    float acc[HIDDEN];
#pragma unroll
    for (int j = 0; j < HIDDEN; ++j) acc[j] = b_sim[j];

    for (int k4 = 0; k4 < IN_DIM / 4; ++k4) {   // 32 scattered loads total
        const float4 a = xr[k4];
#pragma unroll
        for (int j = 0; j < HIDDEN; ++j) {
            acc[j] += a.x * W_sim[(4 * k4 + 0) * HIDDEN + j];
            acc[j] += a.y * W_sim[(4 * k4 + 1) * HIDDEN + j];
            acc[j] += a.z * W_sim[(4 * k4 + 2) * HIDDEN + j];
            acc[j] += a.w * W_sim[(4 * k4 + 3) * HIDDEN + j];
        }
    }

    float g = 0.f;
#pragma unroll
    for (int j = 0; j < HIDDEN; ++j)
        g += tanhf(acc[j]) * w_vec[j];
    weights[node] = 1.f / (1.f + expf(-(g + b_vec[0])));
}

// ---------------------------------------------------------------------------
// Binning: histogram -> segment alloc -> bucket fill.
// ---------------------------------------------------------------------------
__global__ __launch_bounds__(256) void hist_kernel(
    const int* __restrict__ edge_index, int* __restrict__ counts)
{
    const int e = blockIdx.x * 256 + threadIdx.x;
    if (e < N_EDGES) atomicAdd(&counts[edge_index[e]], 1);
}

__global__ __launch_bounds__(256) void alloc_kernel(
    const int* __restrict__ counts, int* __restrict__ base, int* __restrict__ counter)
{
    const int node = blockIdx.x * 256 + threadIdx.x;
    const int lane = threadIdx.x & 63;
    const int c = (node < N_NODES) ? counts[node] : 0;

    int incl = c;
#pragma unroll
    for (int off = 1; off < 64; off <<= 1) {
        int v = __shfl_up(incl, off, 64);
        if (lane >= off) incl += v;
    }
    const int excl = incl - c;
    int wbase = 0;
    if (lane == 63) wbase = atomicAdd(counter, incl);
    wbase = __shfl(wbase, 63, 64);

    if (node < N_NODES) base[node] = wbase + excl;
}

__global__ __launch_bounds__(256) void fill_kernel(
    const int* __restrict__ edge_index, const int* __restrict__ base,
    int* __restrict__ cursor, int* __restrict__ bucket)
{
    const int e = blockIdx.x * 256 + threadIdx.x;
    if (e >= N_EDGES) return;
    const int row = edge_index[e];
    const int col = edge_index[N_EDGES + e];
    const int pos = atomicAdd(&cursor[row], 1);
    bucket[base[row] + pos] = col;
}

// ---------------------------------------------------------------------------
// Gather: one wave per node, half-wave edge pairing (unchanged from R5).
// ---------------------------------------------------------------------------
__global__ __launch_bounds__(256) void gather_kernel(
    const float* __restrict__ x, const float* __restrict__ weights,
    const int* __restrict__ counts, const int* __restrict__ base,
    const int* __restrict__ bucket, float* __restrict__ readout)
{
    const int wave = threadIdx.x >> 6;
    const int lane = threadIdx.x & 63;
    const int half = lane >> 5;
    const int l32  = lane & 31;
    const int node = blockIdx.x * 4 + wave;
    if (node >= N_NODES) return;

    const int m = counts[node];
    const int b = base[node];

    float4 acc = make_float4(0.f, 0.f, 0.f, 0.f);
    for (int i = half; i < m; i += 2) {
        const int col = bucket[b + i];
        const float w = weights[col];
        const float4 xv = ((const float4*)(x + (size_t)col * IN_DIM))[l32];
        acc.x += xv.x * w;
        acc.y += xv.y * w;
        acc.z += xv.z * w;
        acc.w += xv.w * w;
    }
    acc.x += __shfl(acc.x, lane ^ 32, 64);
    acc.y += __shfl(acc.y, lane ^ 32, 64);
    acc.z += __shfl(acc.z, lane ^ 32, 64);
    acc.w += __shfl(acc.w, lane ^ 32, 64);

    if (half == 0)
        ((float4*)(readout + (size_t)node * IN_DIM))[l32] = acc;
}

// ---------------------------------------------------------------------------
// Fallback scatter (only if ws too small for binning).
// ---------------------------------------------------------------------------
__global__ __launch_bounds__(256) void scatter_kernel(
    const float* __restrict__ x, const int* __restrict__ edge_index,
    const float* __restrict__ weights, float* __restrict__ readout)
{
    const int gid = blockIdx.x * 256 + threadIdx.x;
    const int e = gid >> 5;
    const int c = gid & 31;
    if (e >= N_EDGES) return;
    const int row = edge_index[e];
    const int col = edge_index[N_EDGES + e];
    const float w = weights[col];
    const float4 xv = ((const float4*)(x + (size_t)col * IN_DIM))[c];
    float* dst = readout + (size_t)row * IN_DIM + c * 4;
    atomicAdd(dst + 0, xv.x * w);
    atomicAdd(dst + 1, xv.y * w);
    atomicAdd(dst + 2, xv.z * w);
    atomicAdd(dst + 3, xv.w * w);
}

// ---------------------------------------------------------------------------
// Prompt v6: one THREAD per node (R5 structure: no barrier, no duplication).
// Layer1 is a SINGLE k-sweep with h[64] fully resident -> row read once
// (32 scattered loads, was 128). Layer2 unchanged from R5 (jc chunks of 16,
// k2 fully unrolled so h[] indices are constant).
// In-place safe: thread reads only its own out-row, writes it after layer1.
// ---------------------------------------------------------------------------
__global__ __launch_bounds__(256) void prompt_kernel(
    const float* __restrict__ x, float* __restrict__ out /* = readout */,
    const float* __restrict__ W1, const float* __restrict__ b1,
    const float* __restrict__ W2, const float* __restrict__ b2)
{
    const int node = blockIdx.x * 256 + threadIdx.x;
    if (node >= N_NODES) return;

    const float4* rr = (const float4*)(out + (size_t)node * IN_DIM);

    float h[HIDDEN];
#pragma unroll
    for (int j = 0; j < HIDDEN; ++j) h[j] = b1[j];

    for (int k4 = 0; k4 < IN_DIM / 4; ++k4) {   // 32 scattered loads total
        const float4 a = rr[k4];
#pragma unroll
        for (int j = 0; j < HIDDEN; ++j) {
            h[j] += a.x * W1[(4 * k4 + 0) * HIDDEN + j];
            h[j] += a.y * W1[(4 * k4 + 1) * HIDDEN + j];
            h[j] += a.z * W1[(4 * k4 + 2) * HIDDEN + j];
            h[j] += a.w * W1[(4 * k4 + 3) * HIDDEN + j];
        }
    }
#pragma unroll
    for (int j = 0; j < HIDDEN; ++j)
        h[j] = fmaxf(h[j], 0.f);

    const float4* xr4 = (const float4*)(x + (size_t)node * IN_DIM);
    float4* or4 = (float4*)(out + (size_t)node * IN_DIM);

    for (int jc = 0; jc < IN_DIM; jc += 16) {
        float acc[16];
#pragma unroll
        for (int jj = 0; jj < 16; ++jj) acc[jj] = b2[jc + jj];
#pragma unroll
        for (int k2 = 0; k2 < HIDDEN; ++k2) {    // constant h index
            const float hk = h[k2];
#pragma unroll
            for (int jj = 0; jj < 16; ++jj)
                acc[jj] += hk * W2[k2 * IN_DIM + jc + jj];
        }
#pragma unroll
        for (int q = 0; q < 4; ++q) {
            const float4 xv = xr4[jc / 4 + q];
            float4 o;
            o.x = xv.x + acc[4 * q + 0];
            o.y = xv.y + acc[4 * q + 1];
            o.z = xv.z + acc[4 * q + 2];
            o.w = xv.w + acc[4 * q + 3];
            or4[jc / 4 + q] = o;
        }
    }
}

// ---------------------------------------------------------------------------
extern "C" void kernel_launch(void* const* d_in, const int* in_sizes, int n_in,
                              void* d_out, int out_size, void* d_ws, size_t ws_size,
                              hipStream_t stream)
{
    const float* x          = (const float*)d_in[0];
    const int*   edge_index = (const int*)d_in[1];   // int32 (JAX x64 disabled)
    const float* W_sim      = (const float*)d_in[2];
    const float* b_sim      = (const float*)d_in[3];
    const float* w_vec      = (const float*)d_in[4];
    const float* b_vec      = (const float*)d_in[5];
    const float* W1         = (const float*)d_in[6];
    const float* b1         = (const float*)d_in[7];
    const float* W2         = (const float*)d_in[8];
    const float* b2         = (const float*)d_in[9];

    float* out = (float*)d_out;
    float* wsf = (float*)d_ws;
    int*   wsi = (int*)d_ws;

    float* weights = wsf + WS_WEIGHTS;

    gate_kernel<<<(N_NODES + 255) / 256, 256, 0, stream>>>(x, W_sim, b_sim, w_vec, b_vec, weights);

    if (ws_size >= (size_t)WS_TOTAL * 4) {
        int* counts  = wsi + WS_COUNTS;
        int* cursor  = wsi + WS_CURSOR;
        int* counter = wsi + WS_COUNTER;
        int* base    = wsi + WS_BASE;
        int* bucket  = wsi + WS_BUCKET;

        const int nz = WS_BASE - WS_COUNTS;  // counts+cursor+counter contiguous
        zero_int_kernel<<<(nz + 255) / 256, 256, 0, stream>>>(wsi + WS_COUNTS, nz);

        hist_kernel<<<(N_EDGES + 255) / 256, 256, 0, stream>>>(edge_index, counts);
        alloc_kernel<<<(N_NODES + 255) / 256, 256, 0, stream>>>(counts, base, counter);
        fill_kernel<<<(N_EDGES + 255) / 256, 256, 0, stream>>>(edge_index, base, cursor, bucket);
        gather_kernel<<<N_NODES / 4, 256, 0, stream>>>(x, weights, counts, base, bucket, out);
    } else {
        const int n4 = N_NODES * IN_DIM / 4;
        zero_f4_kernel<<<(n4 + 255) / 256, 256, 0, stream>>>((float4*)out, n4);
        scatter_kernel<<<(N_EDGES * 32) / 256, 256, 0, stream>>>(x, edge_index, weights, out);
    }

    prompt_kernel<<<(N_NODES + 255) / 256, 256, 0, stream>>>(x, out, W1, b1, W2, b2);
}